// Round 1
// baseline (200.037 us; speedup 1.0000x reference)
//
#include <hip/hip_runtime.h>

#define BATCH 16
#define TT 60
#define NCLS 80

struct TruthData {
    float tx, ty, tw, th;
    float scale, vx, vy, vw, vh;
    int valid, best, cell, cls;
};

__device__ TruthData g_truth[3][BATCH][TT];
__device__ int g_hasmatch[3][BATCH];

__constant__ float c_anchors[9][2] = {
    {12.f,16.f},{19.f,36.f},{40.f,28.f},{36.f,75.f},{76.f,55.f},
    {72.f,146.f},{142.f,110.f},{192.f,243.f},{459.f,401.f}
};

__device__ __forceinline__ float sigf(float x){ return 1.0f/(1.0f+expf(-x)); }
__device__ __forceinline__ float clogf_(float x){ return fmaxf(logf(x), -100.0f); }
__device__ __forceinline__ float bcef(float p, float t){
    return -(t*clogf_(p) + (1.0f-t)*clogf_(1.0f-p));
}

__global__ void init_kernel(float* out){
    if (threadIdx.x < 6) out[threadIdx.x] = 0.0f;
}

// One block per (level, batch); thread t handles truth t.
__global__ void prep_kernel(const float* __restrict__ labels){
    int lvl = blockIdx.x / BATCH;
    int b = blockIdx.x - lvl*BATCH;
    int t = threadIdx.x;
    const float stride = (float)(8 << lvl);
    const int fs = (lvl==0) ? 76 : ((lvl==1) ? 38 : 19);
    bool best = false;
    if (t < TT) {
        const float* lab = labels + ((size_t)b*TT + t)*5;
        float l0=lab[0], l1=lab[1], l2=lab[2], l3=lab[3], l4=lab[4];
        bool valid = ((((l0+l1)+l2)+l3)+l4) > 0.0f;
        float tx = (l2+l0)/(stride*2.0f);
        float ty = (l3+l1)/(stride*2.0f);
        float tw = (l2-l0)/stride;
        float th = (l3-l1)/stride;
        int txi = (int)tx, tyi = (int)ty;
        int ii = txi < 0 ? 0 : (txi > fs-1 ? fs-1 : txi);
        int jj = tyi < 0 ? 0 : (tyi > fs-1 ? fs-1 : tyi);
        int best_all = 0;
        if (valid) {
            float bestv = 0.0f;
            for (int k=0;k<9;k++){
                float wb = c_anchors[k][0]/stride;
                float hb = c_anchors[k][1]/stride;
                float iw = fminf(tw,wb), ih = fminf(th,hb);
                float en = (iw>0.0f && ih>0.0f) ? 1.0f : 0.0f;
                float ai = iw*ih*en;
                float au = tw*th + wb*hb - ai;
                float iou = ai/au;
                float mw = fmaxf(tw,wb), mh = fmaxf(th,hb);
                float c2 = mw*mw + mh*mh + 1e-16f;
                float rho2 = ((tw-wb)*(tw-wb)+(th-hb)*(th-hb))*0.25f;
                float da = atanf(tw/th) - atanf(wb/hb);
                float v = 0.40528473456935109f*da*da;   // 4/pi^2
                float alpha = v/((1.0f-iou)+v);
                float ci = iou - (rho2/c2 + v*alpha);
                if (k==0 || ci > bestv){ bestv=ci; best_all=k; }  // first-max wins
            }
        }
        int best_n = best_all % 3;
        best = valid && ((best_all/3) == lvl);
        TruthData td;
        td.tx=tx; td.ty=ty; td.tw=tw; td.th=th;
        td.valid = valid ? 1 : 0;
        td.best = best ? 1 : 0;
        td.cell = (best_n*fs + jj)*fs + ii;
        td.cls = (int)l4;
        td.scale = sqrtf(2.0f - tw*th/(float)(fs*fs));
        td.vx = tx - truncf(tx);
        td.vy = ty - truncf(ty);
        float aw = c_anchors[3*lvl+best_n][0]/stride;
        float ah = c_anchors[3*lvl+best_n][1]/stride;
        td.vw = logf(tw/aw + 1e-16f);
        td.vh = logf(th/ah + 1e-16f);
        g_truth[lvl][b][t] = td;
    }
    unsigned long long m = __ballot(best);
    if (t == 0) g_hasmatch[lvl][b] = (m != 0ULL) ? 1 : 0;
}

// One thread per cell (a, j, i) of one batch. blockIdx.y = batch.
__global__ __launch_bounds__(256) void level_kernel(
    const float* __restrict__ x, float* __restrict__ out, int lvl, int fs)
{
    const float stride = (float)(8 << lvl);
    const int fs2 = fs*fs;
    const int ncell = 3*fs2;
    const int b = blockIdx.y;
    const int tid = threadIdx.x;
    const int lin = blockIdx.x*256 + tid;

    __shared__ float s_tx[TT], s_ty[TT], s_tw[TT], s_th[TT];
    __shared__ float s_scale[TT], s_vx[TT], s_vy[TT], s_vw[TT], s_vh[TT];
    __shared__ int s_vb[TT], s_cell[TT], s_cls[TT];
    if (tid < TT) {
        TruthData td = g_truth[lvl][b][tid];
        s_tx[tid]=td.tx; s_ty[tid]=td.ty; s_tw[tid]=td.tw; s_th[tid]=td.th;
        s_scale[tid]=td.scale; s_vx[tid]=td.vx; s_vy[tid]=td.vy;
        s_vw[tid]=td.vw; s_vh[tid]=td.vh;
        s_vb[tid] = td.valid | (td.best<<1);
        s_cell[tid]=td.cell; s_cls[tid]=td.cls;
    }
    __syncthreads();
    const int hm = g_hasmatch[lvl][b];

    float lxy=0.f, lwh=0.f, lobj=0.f, lcls=0.f, ll2=0.f;
    if (lin < ncell) {
        int a = lin / fs2;
        int rem = lin - a*fs2;
        int j = rem / fs;
        int i = rem - j*fs;
        const float* xb = x + ((size_t)b*255 + a*85)*fs2 + rem;
        float v0 = xb[0];
        float v1 = xb[(size_t)fs2];
        float v2 = xb[(size_t)2*fs2];
        float v3 = xb[(size_t)3*fs2];
        float v4 = xb[(size_t)4*fs2];
        float sx = sigf(v0), sy = sigf(v1), sobj = sigf(v4);
        float aw = c_anchors[3*lvl+a][0]/stride;
        float ah = c_anchors[3*lvl+a][1]/stride;
        float px = sx + (float)i;
        float py = sy + (float)j;
        float pw = expf(v2)*aw;
        float ph = expf(v3)*ah;
        float hpw = 0.5f*pw, hph = 0.5f*ph;
        float area_p = pw*ph;
        float maxiou = 0.0f;
        int mt = -1;                       // last matching truth wins (np scatter order)
        for (int t=0;t<TT;t++){
            int vb = s_vb[t];
            if (vb & 1) {
                float tw_ = s_tw[t], th_ = s_th[t];
                float tlx = fmaxf(px-hpw, s_tx[t]-0.5f*tw_);
                float tly = fmaxf(py-hph, s_ty[t]-0.5f*th_);
                float brx = fminf(px+hpw, s_tx[t]+0.5f*tw_);
                float bry = fminf(py+hph, s_ty[t]+0.5f*th_);
                if (tlx < brx && tly < bry) {
                    float ai = (brx-tlx)*(bry-tly);
                    float iou = ai/((area_p + tw_*th_) - ai);
                    maxiou = fmaxf(maxiou, iou);
                }
                if ((vb & 2) && s_cell[t] == lin) mt = t;
            }
        }
        float om = hm ? ((maxiou > 0.5f) ? 0.0f : 1.0f) : 1.0f;
        float t4 = 0.0f;
        if (mt >= 0) { om = 1.0f; t4 = 1.0f; }
        float oo = sobj*om, to = t4*om;
        lobj = bcef(oo, to);
        float d = oo - to;
        ll2 = d*d;
        if (mt >= 0) {
            // matched cell: tgt_mask=1 -> needs xy/wh/cls terms + 80 class channels
            float sc = s_scale[mt], w2 = sc*sc;
            float vx = s_vx[mt], vy = s_vy[mt];
            lxy = w2*(bcef(sx,vx) + bcef(sy,vy));
            float dx = sx-vx, dy = sy-vy;
            float dw = sc*(v2 - s_vw[mt]);
            float dh = sc*(v3 - s_vh[mt]);
            lwh = 0.5f*(dw*dw + dh*dh);
            ll2 += dx*dx + dy*dy + dw*dw + dh*dh;
            int cls = s_cls[mt];
            for (int c=0;c<NCLS;c++){
                float p = sigf(xb[(size_t)(5+c)*fs2]);
                float ttg = (c==cls) ? 1.0f : 0.0f;
                lcls += bcef(p, ttg);
                float dc = p - ttg;
                ll2 += dc*dc;
            }
        }
    }
    // block reduction: wave64 shuffle, then cross-wave via LDS
    for (int off=32; off>0; off>>=1){
        lxy  += __shfl_down(lxy,  off);
        lwh  += __shfl_down(lwh,  off);
        lobj += __shfl_down(lobj, off);
        lcls += __shfl_down(lcls, off);
        ll2  += __shfl_down(ll2,  off);
    }
    __shared__ float red[4][5];
    int wid = tid >> 6, ln = tid & 63;
    if (ln == 0){ red[wid][0]=lxy; red[wid][1]=lwh; red[wid][2]=lobj; red[wid][3]=lcls; red[wid][4]=ll2; }
    __syncthreads();
    if (tid == 0){
        atomicAdd(&out[1], red[0][0]+red[1][0]+red[2][0]+red[3][0]);
        atomicAdd(&out[2], red[0][1]+red[1][1]+red[2][1]+red[3][1]);
        atomicAdd(&out[3], red[0][2]+red[1][2]+red[2][2]+red[3][2]);
        atomicAdd(&out[4], red[0][3]+red[1][3]+red[2][3]+red[3][3]);
        atomicAdd(&out[5], red[0][4]+red[1][4]+red[2][4]+red[3][4]);
    }
}

__global__ void fin_kernel(float* out){
    out[0] = out[1]+out[2]+out[3]+out[4];
}

extern "C" void kernel_launch(void* const* d_in, const int* in_sizes, int n_in,
                              void* d_out, int out_size, void* d_ws, size_t ws_size,
                              hipStream_t stream) {
    const float* x0 = (const float*)d_in[0];
    const float* x1 = (const float*)d_in[1];
    const float* x2 = (const float*)d_in[2];
    const float* labels = (const float*)d_in[3];
    float* out = (float*)d_out;

    init_kernel<<<1, 64, 0, stream>>>(out);
    prep_kernel<<<3*BATCH, 64, 0, stream>>>(labels);
    level_kernel<<<dim3((3*76*76+255)/256, BATCH), 256, 0, stream>>>(x0, out, 0, 76);
    level_kernel<<<dim3((3*38*38+255)/256, BATCH), 256, 0, stream>>>(x1, out, 1, 38);
    level_kernel<<<dim3((3*19*19+255)/256, BATCH), 256, 0, stream>>>(x2, out, 2, 19);
    fin_kernel<<<1, 1, 0, stream>>>(out);
}

// Round 2
// 62.460 us; speedup vs baseline: 3.2026x; 3.2026x over previous
//
#include <hip/hip_runtime.h>

#define BATCH 16
#define TT 60
#define NCLS 80
#define NLVL 3

// blocks per (lvl) in x: lvl0 ceil(17328/256)=68, lvl1 ceil(4332/256)=17, lvl2 ceil(1083/256)=5
#define NB0 68
#define NB1 17
#define NB2 5
#define NBX (NB0 + NB1 + NB2)
#define NBLK (NBX * BATCH)

struct MatchData { float vx, vy, vw, vh, scale; int cls; };

__device__ float4    g_box[NLVL][BATCH][TT];   // tlx, tly, brx, bry (compacted valid)
__device__ float     g_area[NLVL][BATCH][TT];  // tw*th
__device__ int       g_mcell[NLVL][BATCH][TT]; // matched cell ids (compacted best)
__device__ MatchData g_mdat[NLVL][BATCH][TT];
__device__ int       g_nvalid[NLVL][BATCH];
__device__ int       g_nmatch[NLVL][BATCH];

__constant__ float c_anchors[9][2] = {
    {12.f,16.f},{19.f,36.f},{40.f,28.f},{36.f,75.f},{76.f,55.f},
    {72.f,146.f},{142.f,110.f},{192.f,243.f},{459.f,401.f}
};

__device__ __forceinline__ float sigf(float x){ return 1.0f/(1.0f+expf(-x)); }
__device__ __forceinline__ float clogf_(float x){ return fmaxf(logf(x), -100.0f); }
__device__ __forceinline__ float bcef(float p, float t){
    return -(t*clogf_(p) + (1.0f-t)*clogf_(1.0f-p));
}

// One block per (level, batch); thread t handles truth t; ballot-compaction.
__global__ void prep_kernel(const float* __restrict__ labels){
    int lvl = blockIdx.x / BATCH;
    int b = blockIdx.x - lvl*BATCH;
    int t = threadIdx.x;
    const float stride = (float)(8 << lvl);
    const int fs = (lvl==0) ? 76 : ((lvl==1) ? 38 : 19);
    bool valid = false, best = false;
    float tx=0, ty=0, tw=0, th=0;
    int cell = 0, cls = 0;
    float scale=0, vx=0, vy=0, vw=0, vh=0;
    if (t < TT) {
        const float* lab = labels + ((size_t)b*TT + t)*5;
        float l0=lab[0], l1=lab[1], l2=lab[2], l3=lab[3], l4=lab[4];
        valid = ((((l0+l1)+l2)+l3)+l4) > 0.0f;
        tx = (l2+l0)/(stride*2.0f);
        ty = (l3+l1)/(stride*2.0f);
        tw = (l2-l0)/stride;
        th = (l3-l1)/stride;
        int txi = (int)tx, tyi = (int)ty;
        int ii = txi < 0 ? 0 : (txi > fs-1 ? fs-1 : txi);
        int jj = tyi < 0 ? 0 : (tyi > fs-1 ? fs-1 : tyi);
        int best_all = 0;
        if (valid) {
            float bestv = 0.0f;
            for (int k=0;k<9;k++){
                float wb = c_anchors[k][0]/stride;
                float hb = c_anchors[k][1]/stride;
                float iw = fminf(tw,wb), ih = fminf(th,hb);
                float en = (iw>0.0f && ih>0.0f) ? 1.0f : 0.0f;
                float ai = iw*ih*en;
                float au = tw*th + wb*hb - ai;
                float iou = ai/au;
                float mw = fmaxf(tw,wb), mh = fmaxf(th,hb);
                float c2 = mw*mw + mh*mh + 1e-16f;
                float rho2 = ((tw-wb)*(tw-wb)+(th-hb)*(th-hb))*0.25f;
                float da = atanf(tw/th) - atanf(wb/hb);
                float v = 0.40528473456935109f*da*da;   // 4/pi^2
                float alpha = v/((1.0f-iou)+v);
                float ci = iou - (rho2/c2 + v*alpha);
                if (k==0 || ci > bestv){ bestv=ci; best_all=k; }  // first-max wins
            }
        }
        int best_n = best_all % 3;
        best = valid && ((best_all/3) == lvl);
        cell = (best_n*fs + jj)*fs + ii;
        cls = (int)l4;
        scale = sqrtf(2.0f - tw*th/(float)(fs*fs));
        vx = tx - truncf(tx);
        vy = ty - truncf(ty);
        float aw = c_anchors[3*lvl+best_n][0]/stride;
        float ah = c_anchors[3*lvl+best_n][1]/stride;
        vw = logf(tw/aw + 1e-16f);
        vh = logf(th/ah + 1e-16f);
    }
    unsigned long long vm = __ballot(valid);
    unsigned long long bm = __ballot(best);
    unsigned long long below = (t == 0) ? 0ULL : ((1ULL << t) - 1ULL);
    if (valid) {
        int r = __popcll(vm & below);
        g_box[lvl][b][r] = make_float4(tx - 0.5f*tw, ty - 0.5f*th, tx + 0.5f*tw, ty + 0.5f*th);
        g_area[lvl][b][r] = tw*th;
    }
    if (best) {
        int r = __popcll(bm & below);
        g_mcell[lvl][b][r] = cell;
        MatchData md; md.vx=vx; md.vy=vy; md.vw=vw; md.vh=vh; md.scale=scale; md.cls=cls;
        g_mdat[lvl][b][r] = md;
    }
    if (t == 0) {
        g_nvalid[lvl][b] = __popcll(vm);
        g_nmatch[lvl][b] = __popcll(bm);
    }
}

// Fused over all 3 levels: blockIdx.x in [0,90) selects (level, local block), blockIdx.y = batch.
__global__ __launch_bounds__(256) void loss_kernel(
    const float* __restrict__ x0, const float* __restrict__ x1,
    const float* __restrict__ x2, float* __restrict__ ws)
{
    const int bx = blockIdx.x, b = blockIdx.y, tid = threadIdx.x;
    int lvl, lb, fs;
    const float* x;
    if (bx < NB0)            { lvl = 0; lb = bx;            x = x0; fs = 76; }
    else if (bx < NB0 + NB1) { lvl = 1; lb = bx - NB0;      x = x1; fs = 38; }
    else                     { lvl = 2; lb = bx - NB0 - NB1; x = x2; fs = 19; }
    const float stride = (float)(8 << lvl);
    const int fs2 = fs*fs;
    const int ncell = 3*fs2;
    const int lin = lb*256 + tid;

    __shared__ float4 s_box[TT];
    __shared__ float  s_area[TT];
    __shared__ int    s_mcell[TT];
    const int nv = g_nvalid[lvl][b];
    const int nm = g_nmatch[lvl][b];
    if (tid < nv) { s_box[tid] = g_box[lvl][b][tid]; s_area[tid] = g_area[lvl][b][tid]; }
    if (tid < nm) { s_mcell[tid] = g_mcell[lvl][b][tid]; }
    __syncthreads();

    float lxy=0.f, lwh=0.f, lobj=0.f, lcls=0.f, ll2=0.f;
    if (lin < ncell) {
        const int a = lin / fs2;
        const int rem = lin - a*fs2;
        const int j = rem / fs;
        const int i = rem - j*fs;
        const float* xb = x + ((size_t)b*255 + a*85)*fs2 + rem;
        const float v0 = xb[0];
        const float v1 = xb[(size_t)fs2];
        const float v2 = xb[(size_t)2*fs2];
        const float v3 = xb[(size_t)3*fs2];
        const float v4 = xb[(size_t)4*fs2];
        const float sx = sigf(v0), sy = sigf(v1), sobj = sigf(v4);
        const float aw = c_anchors[3*lvl+a][0]/stride;
        const float ah = c_anchors[3*lvl+a][1]/stride;
        const float px = sx + (float)i;
        const float py = sy + (float)j;
        const float pw = expf(v2)*aw;
        const float ph = expf(v3)*ah;
        const float area_p = pw*ph;

        // last matching best-truth wins (np scatter order; compaction is stable)
        int mt = -1;
        for (int k=0;k<nm;k++) if (s_mcell[k] == lin) mt = k;

        // ignore mask: exists valid truth with IoU > 0.5  <=>  3*area_i > area_p + area_t
        bool ign = false;
        if (nm > 0 && mt < 0) {
            const float pxl = px - 0.5f*pw, pxr = px + 0.5f*pw;
            const float pyl = py - 0.5f*ph, pyr = py + 0.5f*ph;
            #pragma unroll 4
            for (int t=0;t<nv;t++){
                float4 tb = s_box[t];
                float w = fminf(pxr, tb.z) - fmaxf(pxl, tb.x);
                float h = fminf(pyr, tb.w) - fmaxf(pyl, tb.y);
                float ai = w*h;
                ign = ign || ((w > 0.0f) && (h > 0.0f) && (3.0f*ai > area_p + s_area[t]));
            }
        }
        float om = (nm > 0) ? (ign ? 0.0f : 1.0f) : 1.0f;
        float t4 = 0.0f;
        if (mt >= 0) { om = 1.0f; t4 = 1.0f; }
        const float oo = sobj*om, to = t4*om;
        lobj = bcef(oo, to);
        const float d = oo - to;
        ll2 = d*d;
        if (mt >= 0) {
            MatchData md = g_mdat[lvl][b][mt];
            const float sc = md.scale, w2 = sc*sc;
            lxy = w2*(bcef(sx, md.vx) + bcef(sy, md.vy));
            const float dx = sx - md.vx, dy = sy - md.vy;
            const float dw = sc*(v2 - md.vw);
            const float dh = sc*(v3 - md.vh);
            lwh = 0.5f*(dw*dw + dh*dh);
            ll2 += dx*dx + dy*dy + dw*dw + dh*dh;
            const int cls = md.cls;
            for (int c=0;c<NCLS;c++){
                float p = sigf(xb[(size_t)(5+c)*fs2]);
                float ttg = (c==cls) ? 1.0f : 0.0f;
                lcls += bcef(p, ttg);
                float dc = p - ttg;
                ll2 += dc*dc;
            }
        }
    }
    // block reduction: wave64 shuffle, then cross-wave via LDS
    for (int off=32; off>0; off>>=1){
        lxy  += __shfl_down(lxy,  off);
        lwh  += __shfl_down(lwh,  off);
        lobj += __shfl_down(lobj, off);
        lcls += __shfl_down(lcls, off);
        ll2  += __shfl_down(ll2,  off);
    }
    __shared__ float red[4][5];
    const int wid = tid >> 6, ln = tid & 63;
    if (ln == 0){ red[wid][0]=lxy; red[wid][1]=lwh; red[wid][2]=lobj; red[wid][3]=lcls; red[wid][4]=ll2; }
    __syncthreads();
    if (tid == 0){
        const int blk = b*NBX + bx;
        ws[0*NBLK + blk] = red[0][0]+red[1][0]+red[2][0]+red[3][0];
        ws[1*NBLK + blk] = red[0][1]+red[1][1]+red[2][1]+red[3][1];
        ws[2*NBLK + blk] = red[0][2]+red[1][2]+red[2][2]+red[3][2];
        ws[3*NBLK + blk] = red[0][3]+red[1][3]+red[2][3]+red[3][3];
        ws[4*NBLK + blk] = red[0][4]+red[1][4]+red[2][4]+red[3][4];
    }
}

__global__ __launch_bounds__(256) void fin_kernel(const float* __restrict__ ws, float* __restrict__ out){
    const int tid = threadIdx.x;
    float s[5] = {0.f,0.f,0.f,0.f,0.f};
    for (int i = tid; i < NBLK; i += 256){
        #pragma unroll
        for (int c=0;c<5;c++) s[c] += ws[c*NBLK + i];
    }
    for (int off=32; off>0; off>>=1){
        #pragma unroll
        for (int c=0;c<5;c++) s[c] += __shfl_down(s[c], off);
    }
    __shared__ float red[4][5];
    const int wid = tid >> 6, ln = tid & 63;
    if (ln == 0){ for (int c=0;c<5;c++) red[wid][c] = s[c]; }
    __syncthreads();
    if (tid == 0){
        float t0 = red[0][0]+red[1][0]+red[2][0]+red[3][0];
        float t1 = red[0][1]+red[1][1]+red[2][1]+red[3][1];
        float t2 = red[0][2]+red[1][2]+red[2][2]+red[3][2];
        float t3 = red[0][3]+red[1][3]+red[2][3]+red[3][3];
        float t4 = red[0][4]+red[1][4]+red[2][4]+red[3][4];
        out[0] = t0+t1+t2+t3;
        out[1] = t0; out[2] = t1; out[3] = t2; out[4] = t3; out[5] = t4;
    }
}

extern "C" void kernel_launch(void* const* d_in, const int* in_sizes, int n_in,
                              void* d_out, int out_size, void* d_ws, size_t ws_size,
                              hipStream_t stream) {
    const float* x0 = (const float*)d_in[0];
    const float* x1 = (const float*)d_in[1];
    const float* x2 = (const float*)d_in[2];
    const float* labels = (const float*)d_in[3];
    float* out = (float*)d_out;
    float* ws = (float*)d_ws;   // 5 * NBLK floats = 28.8 KB

    prep_kernel<<<NLVL*BATCH, 64, 0, stream>>>(labels);
    loss_kernel<<<dim3(NBX, BATCH), 256, 0, stream>>>(x0, x1, x2, ws);
    fin_kernel<<<1, 256, 0, stream>>>(ws, out);
}

// Round 3
// 46.227 us; speedup vs baseline: 4.3272x; 1.3512x over previous
//
#include <hip/hip_runtime.h>

#define BATCH 16
#define TT 60
#define NCLS 80
#define NLVL 3

// blocks per level in x: lvl0 ceil(17328/256)=68, lvl1 ceil(4332/256)=17, lvl2 ceil(1083/256)=5
#define NB0 68
#define NB1 17
#define NB2 5
#define NBX (NB0 + NB1 + NB2)
#define NBLK (NBX * BATCH)
#define MAXM (TT * BATCH)   // each truth matches exactly one level -> <=960 matched cells

struct MatchData { float vx, vy, vw, vh, scale; int cls; };
struct MWork { int xoff; int fs2; int lvl; int cls; };

__device__ float4    g_box[NLVL][BATCH][TT];   // tlx, tly, brx, bry (compacted valid)
__device__ int       g_mcell[NLVL][BATCH][TT]; // matched cell ids (compacted best)
__device__ MatchData g_mdat[NLVL][BATCH][TT];
__device__ int       g_nvalid[NLVL][BATCH];
__device__ int       g_nmatch[NLVL][BATCH];
__device__ MWork     g_mwork[MAXM];
__device__ int       g_mcount;
__device__ float     g_cls_extra[2];           // deferred lcls, ll2

__constant__ float c_anchors[9][2] = {
    {12.f,16.f},{19.f,36.f},{40.f,28.f},{36.f,75.f},{76.f,55.f},
    {72.f,146.f},{142.f,110.f},{192.f,243.f},{459.f,401.f}
};

__device__ __forceinline__ float sigf(float x){ return 1.0f/(1.0f+expf(-x)); }
__device__ __forceinline__ float clogf_(float x){ return fmaxf(logf(x), -100.0f); }
__device__ __forceinline__ float bcef(float p, float t){
    return -(t*clogf_(p) + (1.0f-t)*clogf_(1.0f-p));
}

// One block per (level, batch); thread t handles truth t; ballot-compaction.
__global__ void prep_kernel(const float* __restrict__ labels){
    int lvl = blockIdx.x / BATCH;
    int b = blockIdx.x - lvl*BATCH;
    int t = threadIdx.x;
    if (blockIdx.x == 0 && t == 0){ g_mcount = 0; g_cls_extra[0] = 0.f; g_cls_extra[1] = 0.f; }
    const float stride = (float)(8 << lvl);
    const int fs = (lvl==0) ? 76 : ((lvl==1) ? 38 : 19);
    bool valid = false, best = false;
    float tx=0, ty=0, tw=0, th=0;
    int cell = 0, cls = 0;
    float scale=0, vx=0, vy=0, vw=0, vh=0;
    if (t < TT) {
        const float* lab = labels + ((size_t)b*TT + t)*5;
        float l0=lab[0], l1=lab[1], l2=lab[2], l3=lab[3], l4=lab[4];
        valid = ((((l0+l1)+l2)+l3)+l4) > 0.0f;
        tx = (l2+l0)/(stride*2.0f);
        ty = (l3+l1)/(stride*2.0f);
        tw = (l2-l0)/stride;
        th = (l3-l1)/stride;
        int txi = (int)tx, tyi = (int)ty;
        int ii = txi < 0 ? 0 : (txi > fs-1 ? fs-1 : txi);
        int jj = tyi < 0 ? 0 : (tyi > fs-1 ? fs-1 : tyi);
        int best_all = 0;
        if (valid) {
            float bestv = 0.0f;
            for (int k=0;k<9;k++){
                float wb = c_anchors[k][0]/stride;
                float hb = c_anchors[k][1]/stride;
                float iw = fminf(tw,wb), ih = fminf(th,hb);
                float en = (iw>0.0f && ih>0.0f) ? 1.0f : 0.0f;
                float ai = iw*ih*en;
                float au = tw*th + wb*hb - ai;
                float iou = ai/au;
                float mw = fmaxf(tw,wb), mh = fmaxf(th,hb);
                float c2 = mw*mw + mh*mh + 1e-16f;
                float rho2 = ((tw-wb)*(tw-wb)+(th-hb)*(th-hb))*0.25f;
                float da = atanf(tw/th) - atanf(wb/hb);
                float v = 0.40528473456935109f*da*da;   // 4/pi^2
                float alpha = v/((1.0f-iou)+v);
                float ci = iou - (rho2/c2 + v*alpha);
                if (k==0 || ci > bestv){ bestv=ci; best_all=k; }  // first-max wins
            }
        }
        int best_n = best_all % 3;
        best = valid && ((best_all/3) == lvl);
        cell = (best_n*fs + jj)*fs + ii;
        cls = (int)l4;
        scale = sqrtf(2.0f - tw*th/(float)(fs*fs));
        vx = tx - truncf(tx);
        vy = ty - truncf(ty);
        float aw = c_anchors[3*lvl+best_n][0]/stride;
        float ah = c_anchors[3*lvl+best_n][1]/stride;
        vw = logf(tw/aw + 1e-16f);
        vh = logf(th/ah + 1e-16f);
    }
    unsigned long long vm = __ballot(valid);
    unsigned long long bm = __ballot(best);
    unsigned long long below = (t == 0) ? 0ULL : ((1ULL << t) - 1ULL);
    if (valid) {
        int r = __popcll(vm & below);
        g_box[lvl][b][r] = make_float4(tx - 0.5f*tw, ty - 0.5f*th, tx + 0.5f*tw, ty + 0.5f*th);
    }
    if (best) {
        int r = __popcll(bm & below);
        g_mcell[lvl][b][r] = cell;
        MatchData md; md.vx=vx; md.vy=vy; md.vw=vw; md.vh=vh; md.scale=scale; md.cls=cls;
        g_mdat[lvl][b][r] = md;
    }
    if (t == 0) {
        g_nvalid[lvl][b] = __popcll(vm);
        g_nmatch[lvl][b] = __popcll(bm);
    }
}

// Fused over all 3 levels: blockIdx.x in [0,90) selects (level, local block), blockIdx.y = batch.
__global__ __launch_bounds__(256) void loss_kernel(
    const float* __restrict__ x0, const float* __restrict__ x1,
    const float* __restrict__ x2, float* __restrict__ ws)
{
    const int bx = blockIdx.x, b = blockIdx.y, tid = threadIdx.x;
    int lvl, lb, fs;
    const float* x;
    if (bx < NB0)            { lvl = 0; lb = bx;             x = x0; fs = 76; }
    else if (bx < NB0 + NB1) { lvl = 1; lb = bx - NB0;       x = x1; fs = 38; }
    else                     { lvl = 2; lb = bx - NB0 - NB1; x = x2; fs = 19; }
    const float stride = (float)(8 << lvl);
    const int fs2 = fs*fs;
    const int ncell = 3*fs2;
    const int lin = lb*256 + tid;

    __shared__ float4 s_box[TT];
    __shared__ int    s_mcell[TT];
    const int nv = g_nvalid[lvl][b];
    const int nm = g_nmatch[lvl][b];
    if (tid < nv) { s_box[tid] = g_box[lvl][b][tid]; }
    if (tid < nm) { s_mcell[tid] = g_mcell[lvl][b][tid]; }
    __syncthreads();

    float lxy=0.f, lwh=0.f, lobj=0.f, ll2=0.f;
    if (lin < ncell) {
        const int a = lin / fs2;
        const int rem = lin - a*fs2;
        const int j = rem / fs;
        const int i = rem - j*fs;
        const float* xb = x + ((size_t)b*255 + a*85)*fs2 + rem;
        const float v0 = xb[0];
        const float v1 = xb[(size_t)fs2];
        const float v2 = xb[(size_t)2*fs2];
        const float v3 = xb[(size_t)3*fs2];
        const float v4 = xb[(size_t)4*fs2];
        const float sx = sigf(v0), sy = sigf(v1), sobj = sigf(v4);
        const float aw = c_anchors[3*lvl+a][0]/stride;
        const float ah = c_anchors[3*lvl+a][1]/stride;
        const float px = sx + (float)i;
        const float py = sy + (float)j;
        const float pw = expf(v2)*aw;
        const float ph = expf(v3)*ah;
        const float area_p = pw*ph;

        // last matching best-truth wins (np scatter order; compaction is stable)
        int mt = -1;
        for (int k=0;k<nm;k++) if (s_mcell[k] == lin) mt = k;

        // ignore mask: exists valid truth with IoU > 0.5  <=>  3*area_i > area_p + area_t
        bool ign = false;
        if (nm > 0 && mt < 0) {
            const float pxl = px - 0.5f*pw, pxr = px + 0.5f*pw;
            const float pyl = py - 0.5f*ph, pyr = py + 0.5f*ph;
            #pragma unroll 4
            for (int t=0;t<nv;t++){
                float4 tb = s_box[t];
                float w = fminf(pxr, tb.z) - fmaxf(pxl, tb.x);
                float h = fminf(pyr, tb.w) - fmaxf(pyl, tb.y);
                float at = (tb.z - tb.x)*(tb.w - tb.y);
                ign = ign || ((w > 0.0f) && (h > 0.0f) && (3.0f*(w*h) > area_p + at));
            }
        }
        float om = (nm > 0) ? (ign ? 0.0f : 1.0f) : 1.0f;
        float t4 = 0.0f;
        if (mt >= 0) { om = 1.0f; t4 = 1.0f; }
        const float oo = sobj*om, to = t4*om;
        lobj = bcef(oo, to);
        const float d = oo - to;
        ll2 = d*d;
        if (mt >= 0) {
            MatchData md = g_mdat[lvl][b][mt];
            const float sc = md.scale, w2 = sc*sc;
            lxy = w2*(bcef(sx, md.vx) + bcef(sy, md.vy));
            const float dx = sx - md.vx, dy = sy - md.vy;
            const float dw = sc*(v2 - md.vw);
            const float dh = sc*(v3 - md.vh);
            lwh = 0.5f*(dw*dw + dh*dh);
            ll2 += dx*dx + dy*dy + dw*dw + dh*dh;
            // defer the 80-class-channel loop to cls_kernel (one wave per match)
            int idx = atomicAdd(&g_mcount, 1);
            MWork mw;
            mw.xoff = (b*255 + a*85 + 5)*fs2 + rem;
            mw.fs2  = fs2;
            mw.lvl  = lvl;
            mw.cls  = md.cls;
            g_mwork[idx] = mw;
        }
    }
    // block reduction: wave64 shuffle, then cross-wave via LDS
    float lcls = 0.f;  // kept for slot symmetry (deferred part added in fin)
    for (int off=32; off>0; off>>=1){
        lxy  += __shfl_down(lxy,  off);
        lwh  += __shfl_down(lwh,  off);
        lobj += __shfl_down(lobj, off);
        ll2  += __shfl_down(ll2,  off);
    }
    __shared__ float red[4][4];
    const int wid = tid >> 6, ln = tid & 63;
    if (ln == 0){ red[wid][0]=lxy; red[wid][1]=lwh; red[wid][2]=lobj; red[wid][3]=ll2; }
    __syncthreads();
    if (tid == 0){
        const int blk = b*NBX + bx;
        ws[0*NBLK + blk] = red[0][0]+red[1][0]+red[2][0]+red[3][0];
        ws[1*NBLK + blk] = red[0][1]+red[1][1]+red[2][1]+red[3][1];
        ws[2*NBLK + blk] = red[0][2]+red[1][2]+red[2][2]+red[3][2];
        ws[3*NBLK + blk] = red[0][3]+red[1][3]+red[2][3]+red[3][3];
    }
    (void)lcls;
}

// One wave per matched cell: 80 class channels across lanes (64 + 16).
__global__ __launch_bounds__(256) void cls_kernel(
    const float* __restrict__ x0, const float* __restrict__ x1,
    const float* __restrict__ x2)
{
    const int item = blockIdx.x*4 + (threadIdx.x >> 6);
    const int ln = threadIdx.x & 63;
    if (item >= g_mcount) return;
    const MWork w = g_mwork[item];
    const float* x = (w.lvl==0) ? x0 : ((w.lvl==1) ? x1 : x2);
    float lcls = 0.f, ll2 = 0.f;
    {
        float p = sigf(x[(size_t)w.xoff + (size_t)ln*w.fs2]);
        float t = (ln == w.cls) ? 1.0f : 0.0f;
        lcls += bcef(p, t);
        float d = p - t; ll2 += d*d;
    }
    if (ln < NCLS - 64) {
        int c = 64 + ln;
        float p = sigf(x[(size_t)w.xoff + (size_t)c*w.fs2]);
        float t = (c == w.cls) ? 1.0f : 0.0f;
        lcls += bcef(p, t);
        float d = p - t; ll2 += d*d;
    }
    for (int off=32; off>0; off>>=1){
        lcls += __shfl_down(lcls, off);
        ll2  += __shfl_down(ll2,  off);
    }
    if (ln == 0){
        atomicAdd(&g_cls_extra[0], lcls);
        atomicAdd(&g_cls_extra[1], ll2);
    }
}

__global__ __launch_bounds__(256) void fin_kernel(const float* __restrict__ ws, float* __restrict__ out){
    const int tid = threadIdx.x;
    float s[4] = {0.f,0.f,0.f,0.f};
    for (int i = tid; i < NBLK; i += 256){
        #pragma unroll
        for (int c=0;c<4;c++) s[c] += ws[c*NBLK + i];
    }
    for (int off=32; off>0; off>>=1){
        #pragma unroll
        for (int c=0;c<4;c++) s[c] += __shfl_down(s[c], off);
    }
    __shared__ float red[4][4];
    const int wid = tid >> 6, ln = tid & 63;
    if (ln == 0){ for (int c=0;c<4;c++) red[wid][c] = s[c]; }
    __syncthreads();
    if (tid == 0){
        float t_xy  = red[0][0]+red[1][0]+red[2][0]+red[3][0];
        float t_wh  = red[0][1]+red[1][1]+red[2][1]+red[3][1];
        float t_obj = red[0][2]+red[1][2]+red[2][2]+red[3][2];
        float t_l2  = red[0][3]+red[1][3]+red[2][3]+red[3][3];
        float t_cls = g_cls_extra[0];
        t_l2 += g_cls_extra[1];
        out[0] = t_xy + t_wh + t_obj + t_cls;
        out[1] = t_xy; out[2] = t_wh; out[3] = t_obj; out[4] = t_cls; out[5] = t_l2;
    }
}

extern "C" void kernel_launch(void* const* d_in, const int* in_sizes, int n_in,
                              void* d_out, int out_size, void* d_ws, size_t ws_size,
                              hipStream_t stream) {
    const float* x0 = (const float*)d_in[0];
    const float* x1 = (const float*)d_in[1];
    const float* x2 = (const float*)d_in[2];
    const float* labels = (const float*)d_in[3];
    float* out = (float*)d_out;
    float* ws = (float*)d_ws;   // 4 * NBLK floats

    prep_kernel<<<NLVL*BATCH, 64, 0, stream>>>(labels);
    loss_kernel<<<dim3(NBX, BATCH), 256, 0, stream>>>(x0, x1, x2, ws);
    cls_kernel<<<MAXM/4, 256, 0, stream>>>(x0, x1, x2);
    fin_kernel<<<1, 256, 0, stream>>>(ws, out);
}

// Round 4
// 28.568 us; speedup vs baseline: 7.0020x; 1.6181x over previous
//
#include <hip/hip_runtime.h>

#define BATCH 16
#define TT 60
#define NCLS 80
#define NB0 68
#define NB1 17
#define NB2 5
#define NBX (NB0 + NB1 + NB2)
#define NBLK (NBX * BATCH)

__constant__ float c_aw[9] = {12.f,19.f,40.f,36.f,76.f,72.f,142.f,192.f,459.f};
__constant__ float c_ah[9] = {16.f,36.f,28.f,75.f,55.f,146.f,110.f,243.f,401.f};

__device__ __forceinline__ float sigf(float x){ return 1.0f/(1.0f+expf(-x)); }
__device__ __forceinline__ float clogf_(float x){ return fmaxf(logf(x), -100.0f); }
__device__ __forceinline__ float bcef(float p, float t){
    return -(t*clogf_(p) + (1.0f-t)*clogf_(1.0f-p));
}

// Fully fused: per-block truth prep (LDS) + per-cell loss + in-block class queue.
// Grid: x in [0,NBX) selects (level, local block); y = batch.
__global__ __launch_bounds__(256) void main_kernel(
    const float* __restrict__ x0, const float* __restrict__ x1,
    const float* __restrict__ x2, const float* __restrict__ labels,
    float* __restrict__ ws)
{
    const int bx = blockIdx.x, b = blockIdx.y, tid = threadIdx.x;
    int lvl, lb, fs;
    const float* x;
    if (bx < NB0)            { lvl = 0; lb = bx;             x = x0; fs = 76; }
    else if (bx < NB0 + NB1) { lvl = 1; lb = bx - NB0;       x = x1; fs = 38; }
    else                     { lvl = 2; lb = bx - NB0 - NB1; x = x2; fs = 19; }
    const float stride = (float)(8 << lvl);
    const float invs = 1.0f/stride;                // exact (pow2)
    const int fs2 = fs*fs;
    const int ncell = 3*fs2;
    const int lin = lb*256 + tid;

    __shared__ float  s_atan[9];
    __shared__ float4 s_box[TT];                   // valid truths, compacted
    __shared__ int    s_mcell[TT], s_mcls[TT];     // best-matched truths, compacted
    __shared__ float  s_vx[TT], s_vy[TT], s_vw[TT], s_vh[TT], s_sc[TT];
    __shared__ int    s_nv, s_nm, s_qn;
    __shared__ int    s_qoff[TT], s_qcls[TT];

    // ---- stage A: issue global loads early; fill constants
    float v0=0,v1=0,v2=0,v3=0,v4=0;
    int a=0, rem=0, ci=0, cj=0;
    if (lin < ncell) {
        a = lin/fs2; rem = lin - a*fs2; cj = rem/fs; ci = rem - cj*fs;
        const float* xb = x + ((size_t)b*255 + a*85)*(size_t)fs2 + rem;
        v0 = xb[0];
        v1 = xb[(size_t)fs2];
        v2 = xb[(size_t)2*fs2];
        v3 = xb[(size_t)3*fs2];
        v4 = xb[(size_t)4*fs2];
    }
    float l0=0,l1=0,l2=0,l3=0,l4=0;
    if (tid < TT) {
        const float* lab = labels + ((size_t)b*TT + tid)*5;
        l0=lab[0]; l1=lab[1]; l2=lab[2]; l3=lab[3]; l4=lab[4];
    }
    if (tid < 9) s_atan[tid] = atanf(c_aw[tid]/c_ah[tid]);   // stride-invariant
    if (tid == 0) s_qn = 0;
    __syncthreads();

    // ---- stage B: per-truth prep, wave 0 only (lanes = truths)
    if (tid < 64) {
        bool valid=false, best=false;
        float tx=0,ty=0,tw=0,th=0;
        int best_all=0;
        if (tid < TT) {
            valid = ((((l0+l1)+l2)+l3)+l4) > 0.0f;
            tx = (l2+l0)*(0.5f*invs);
            ty = (l3+l1)*(0.5f*invs);
            tw = (l2-l0)*invs;
            th = (l3-l1)*invs;
            if (valid) {
                float ta = atanf(tw/th);
                float twth = tw*th;
                float bestv = 0.0f;
                for (int k=0;k<9;k++){
                    float wb=c_aw[k]*invs, hb=c_ah[k]*invs;
                    float iw=fminf(tw,wb), ih=fminf(th,hb);
                    float en=(iw>0.f && ih>0.f)?1.f:0.f;
                    float ai=iw*ih*en;
                    float au=twth+wb*hb-ai;
                    float iou=ai/au;
                    float mw=fmaxf(tw,wb), mh=fmaxf(th,hb);
                    float c2=mw*mw+mh*mh+1e-16f;
                    float rho2=((tw-wb)*(tw-wb)+(th-hb)*(th-hb))*0.25f;
                    float da=ta-s_atan[k];
                    float v=0.40528473456935109f*da*da;     // 4/pi^2
                    float alpha=v/((1.f-iou)+v);
                    float cv=iou-(rho2/c2+v*alpha);
                    if (k==0 || cv>bestv){ bestv=cv; best_all=k; }  // first-max wins
                }
            }
        }
        int bn = best_all % 3;
        best = valid && ((best_all/3) == lvl);
        unsigned long long vm = __ballot(valid);
        unsigned long long bm = __ballot(best);
        unsigned long long below = (tid==0) ? 0ULL : ((1ULL<<tid)-1ULL);
        if (valid){
            int r = __popcll(vm & below);
            s_box[r] = make_float4(tx-0.5f*tw, ty-0.5f*th, tx+0.5f*tw, ty+0.5f*th);
        }
        if (best){
            int r = __popcll(bm & below);
            int ti=(int)tx, tj=(int)ty;
            int ii = ti<0?0:(ti>fs-1?fs-1:ti);
            int jj = tj<0?0:(tj>fs-1?fs-1:tj);
            s_mcell[r] = (bn*fs+jj)*fs+ii;
            s_mcls[r]  = (int)l4;
            s_sc[r]    = sqrtf(2.f - tw*th/(float)(fs*fs));
            s_vx[r]    = tx - truncf(tx);
            s_vy[r]    = ty - truncf(ty);
            float aw = c_aw[3*lvl+bn]*invs, ah = c_ah[3*lvl+bn]*invs;
            s_vw[r]    = logf(tw/aw + 1e-16f);
            s_vh[r]    = logf(th/ah + 1e-16f);
        }
        if (tid==0){ s_nv = __popcll(vm); s_nm = __popcll(bm); }
    }
    __syncthreads();

    // ---- stage C: per-cell loss
    const int nv = s_nv, nm = s_nm;
    float lxy=0.f, lwh=0.f, lobj=0.f, lcls=0.f, ll2=0.f;
    if (lin < ncell) {
        const float sx = sigf(v0), sy = sigf(v1), sobj = sigf(v4);
        const float aw = c_aw[3*lvl+a]*invs, ah = c_ah[3*lvl+a]*invs;
        const float px = sx + (float)ci;
        const float py = sy + (float)cj;
        const float pw = expf(v2)*aw;
        const float ph = expf(v3)*ah;
        const float area_p = pw*ph;

        int mt = -1;                               // last match wins (np scatter order)
        for (int k=0;k<nm;k++) if (s_mcell[k] == lin) mt = k;

        bool ign = false;                          // IoU>0.5  <=>  3*ai > ap+at
        if (nm > 0 && mt < 0) {
            const float pxl = px-0.5f*pw, pxr = px+0.5f*pw;
            const float pyl = py-0.5f*ph, pyr = py+0.5f*ph;
            #pragma unroll 4
            for (int t=0;t<nv;t++){
                float4 tb = s_box[t];
                float w = fminf(pxr,tb.z) - fmaxf(pxl,tb.x);
                float h = fminf(pyr,tb.w) - fmaxf(pyl,tb.y);
                float at2 = (tb.z-tb.x)*(tb.w-tb.y);
                ign = ign || ((w>0.f)&&(h>0.f)&&(3.f*(w*h) > area_p+at2));
            }
        }
        float om = (nm>0) ? (ign ? 0.f : 1.f) : 1.f;
        float t4 = 0.f;
        if (mt >= 0){ om = 1.f; t4 = 1.f; }
        const float oo = sobj*om, to = t4*om;
        lobj = bcef(oo, to);
        const float d = oo - to;
        ll2 = d*d;
        if (mt >= 0) {
            const float sc = s_sc[mt], w2 = sc*sc;
            const float mvx = s_vx[mt], mvy = s_vy[mt];
            lxy = w2*(bcef(sx,mvx) + bcef(sy,mvy));
            const float dx = sx-mvx, dy = sy-mvy;
            const float dw = sc*(v2 - s_vw[mt]);
            const float dh = sc*(v3 - s_vh[mt]);
            lwh = 0.5f*(dw*dw + dh*dh);
            ll2 += dx*dx + dy*dy + dw*dw + dh*dh;
            int qi = atomicAdd(&s_qn, 1);          // defer class channels to stage D
            s_qoff[qi] = (a*85+5)*fs2 + rem;
            s_qcls[qi] = s_mcls[mt];
        }
    }
    __syncthreads();

    // ---- stage D: class channels, one wave per queued match (80 classes over lanes)
    const int wid = tid>>6, ln = tid&63;
    const int qn = s_qn;
    for (int it = wid; it < qn; it += 4){
        const size_t base = (size_t)b*255*(size_t)fs2 + (size_t)s_qoff[it];
        const int cc = s_qcls[it];
        float p = sigf(x[base + (size_t)ln*fs2]);
        float tt = (ln==cc) ? 1.f : 0.f;
        lcls += bcef(p, tt);
        float dd = p - tt; ll2 += dd*dd;
        if (ln < NCLS-64) {
            int c = 64+ln;
            p = sigf(x[base + (size_t)c*fs2]);
            tt = (c==cc) ? 1.f : 0.f;
            lcls += bcef(p, tt);
            dd = p - tt; ll2 += dd*dd;
        }
    }

    // ---- block reduction
    for (int off=32; off>0; off>>=1){
        lxy  += __shfl_down(lxy,  off);
        lwh  += __shfl_down(lwh,  off);
        lobj += __shfl_down(lobj, off);
        lcls += __shfl_down(lcls, off);
        ll2  += __shfl_down(ll2,  off);
    }
    __shared__ float red[4][5];
    if (ln == 0){ red[wid][0]=lxy; red[wid][1]=lwh; red[wid][2]=lobj; red[wid][3]=lcls; red[wid][4]=ll2; }
    __syncthreads();
    if (tid == 0){
        const int blk = b*NBX + bx;
        ws[0*NBLK + blk] = red[0][0]+red[1][0]+red[2][0]+red[3][0];
        ws[1*NBLK + blk] = red[0][1]+red[1][1]+red[2][1]+red[3][1];
        ws[2*NBLK + blk] = red[0][2]+red[1][2]+red[2][2]+red[3][2];
        ws[3*NBLK + blk] = red[0][3]+red[1][3]+red[2][3]+red[3][3];
        ws[4*NBLK + blk] = red[0][4]+red[1][4]+red[2][4]+red[3][4];
    }
}

__global__ __launch_bounds__(256) void fin_kernel(const float* __restrict__ ws, float* __restrict__ out){
    const int tid = threadIdx.x;
    float s[5] = {0.f,0.f,0.f,0.f,0.f};
    for (int i = tid; i < NBLK; i += 256){
        #pragma unroll
        for (int c=0;c<5;c++) s[c] += ws[c*NBLK + i];
    }
    for (int off=32; off>0; off>>=1){
        #pragma unroll
        for (int c=0;c<5;c++) s[c] += __shfl_down(s[c], off);
    }
    __shared__ float red[4][5];
    const int wid = tid >> 6, ln = tid & 63;
    if (ln == 0){ for (int c=0;c<5;c++) red[wid][c] = s[c]; }
    __syncthreads();
    if (tid == 0){
        float t_xy  = red[0][0]+red[1][0]+red[2][0]+red[3][0];
        float t_wh  = red[0][1]+red[1][1]+red[2][1]+red[3][1];
        float t_obj = red[0][2]+red[1][2]+red[2][2]+red[3][2];
        float t_cls = red[0][3]+red[1][3]+red[2][3]+red[3][3];
        float t_l2  = red[0][4]+red[1][4]+red[2][4]+red[3][4];
        out[0] = t_xy + t_wh + t_obj + t_cls;
        out[1] = t_xy; out[2] = t_wh; out[3] = t_obj; out[4] = t_cls; out[5] = t_l2;
    }
}

extern "C" void kernel_launch(void* const* d_in, const int* in_sizes, int n_in,
                              void* d_out, int out_size, void* d_ws, size_t ws_size,
                              hipStream_t stream) {
    const float* x0 = (const float*)d_in[0];
    const float* x1 = (const float*)d_in[1];
    const float* x2 = (const float*)d_in[2];
    const float* labels = (const float*)d_in[3];
    float* out = (float*)d_out;
    float* ws = (float*)d_ws;   // 5 * NBLK floats = 28.8 KB

    main_kernel<<<dim3(NBX, BATCH), 256, 0, stream>>>(x0, x1, x2, labels, ws);
    fin_kernel<<<1, 256, 0, stream>>>(ws, out);
}